// Round 2
// 632.779 us; speedup vs baseline: 1.3205x; 1.3205x over previous
//
#include <hip/hip_runtime.h>
#include <hip/hip_bf16.h>

typedef __attribute__((ext_vector_type(8))) short short8;
typedef __attribute__((ext_vector_type(4))) float f32x4;

#define HWN 65536
#define WN 256
#define HN 256

// ws float offsets (total ~434 KB)
#define W2N_OFF 0            // 128*9*8 fp32 = 9216
#define W1BF_OFF 9216        // 8*128*64 bf16 = 65536 shorts = 32768 float slots
#define W3BF_OFF 41984       // 8*64*64 bf16 = 16384 float slots
#define W4BF_OFF 58368       // 8*128*64 bf16 = 32768 float slots
#define W5BF_OFF 91136       // 8*64*64 bf16 = 16384 float slots
#define POOL_OFF 107520
#define SCA_OFF 108032

static __device__ __forceinline__ short f2bs(float f) {
    union { __hip_bfloat16 h; short s; } u; u.h = __float2bfloat16(f); return u.s;
}
static __device__ __forceinline__ float bs2f(short s) {
    union { unsigned u; float f; } v; v.u = ((unsigned)(unsigned short)s) << 16; return v.f;
}

__device__ __forceinline__ void norm_row(const float* __restrict__ in,
                                         float* __restrict__ out, int n) {
    float s = 0.f;
    for (int i = 0; i < n; i++) { float v = in[i]; s += v * v; }
    float r = rsqrtf(s);
    for (int i = 0; i < n; i++) out[i] = in[i] * r;
}

__device__ __forceinline__ void norm_row_bf(const float* __restrict__ in,
                                            short* __restrict__ out, int n) {
    float s = 0.f;
    for (int i = 0; i < n; i++) { float v = in[i]; s += v * v; }
    float r = rsqrtf(s);
    for (int i = 0; i < n; i++) out[i] = f2bs(in[i] * r);
}

__global__ void k_prep(const float* __restrict__ w1, const float* __restrict__ w2,
                       const float* __restrict__ w3, const float* __restrict__ w4,
                       const float* __restrict__ w5, float* __restrict__ ws) {
    int r = blockIdx.x * 256 + threadIdx.x;
    short* w1bf = (short*)(ws + W1BF_OFF);
    short* w3bf = (short*)(ws + W3BF_OFF);
    short* w4bf = (short*)(ws + W4BF_OFF);
    short* w5bf = (short*)(ws + W5BF_OFF);
    if (r < 1024) {
        norm_row_bf(w1 + r * 64, w1bf + r * 64, 64);
    } else if (r < 2048) {
        int rr = r - 1024;
        norm_row(w2 + rr * 9, ws + W2N_OFF + rr * 9, 9);
    } else if (r < 2560) {
        int rr = r - 2048;
        norm_row_bf(w3 + rr * 64, w3bf + rr * 64, 64);
    } else if (r < 3584) {
        int rr = r - 2560;
        norm_row_bf(w4 + rr * 64, w4bf + rr * 64, 64);
    } else if (r < 4096) {
        int rr = r - 3584;
        norm_row_bf(w5 + rr * 64, w5bf + rr * 64, 64);
    }
}

// LN1 (in registers, shfl-reduced) + pw1(MFMA) + dw3x3 + gate -> g
// A-fragments live in registers across all cc iterations; LDS is only the
// double-buffered sP (31 KB) -> higher occupancy, 8 barriers instead of 16.
__global__ __launch_bounds__(256, 3) void k1(
    const float* __restrict__ inp, const float* __restrict__ ln1w,
    const float* __restrict__ ln1b, const float* __restrict__ b1,
    const float* __restrict__ b2v, const float* __restrict__ ws,
    float* __restrict__ g) {
    const short* w1bf = (const short*)(ws + W1BF_OFF);
    const float* w2n = ws + W2N_OFF;
    const int b = blockIdx.x >> 8;
    const int tile = blockIdx.x & 255;
    const int x0 = (tile & 15) << 4, y0 = (tile >> 4) << 4;
    const int t = threadIdx.x;
    const int wave = t >> 6, lane = t & 63;
    const int n = lane & 15, q = lane >> 4;

    __shared__ short sP[2][324 * 24];  // bf16 [halo_pix][16 out-ch], stride 24

    // per-lane LN coefs for channels q*8+j (j<8) and 32+q*8+j
    float wc[16], bc[16];
#pragma unroll
    for (int j = 0; j < 8; j++) {
        wc[j] = ln1w[q * 8 + j];
        bc[j] = ln1b[q * 8 + j];
        wc[8 + j] = ln1w[32 + q * 8 + j];
        bc[8 + j] = ln1b[32 + q * 8 + j];
    }

    // Phase A: each wave owns m-tiles mt = wave, wave+4, ... (<21).
    // Lane (n,q) loads its 16 channels of halo pixel mt*16+n, LN via shfl,
    // A-fragments kept in registers.
    short8 afr0[6], afr1[6];
    const float* xb = inp + ((size_t)b << 22);
#pragma unroll
    for (int i = 0; i < 6; i++) {
        int mt = wave + i * 4;
        if (mt < 21) {
            int pix = mt * 16 + n;
            int hy = pix / 18, hx = pix - hy * 18;
            int yy = y0 - 1 + hy, xx = x0 - 1 + hx;
            bool inb = ((unsigned)yy < HN) && ((unsigned)xx < WN) && (pix < 324);
            const float* xin = xb + (yy * WN + xx);
            float x[16];
            float s = 0.f, s2 = 0.f;
#pragma unroll
            for (int j = 0; j < 8; j++) {
                float v0 = inb ? xin[(size_t)(q * 8 + j) << 16] : 0.f;
                float v1 = inb ? xin[(size_t)(32 + q * 8 + j) << 16] : 0.f;
                x[j] = v0; x[8 + j] = v1;
                s += v0 + v1; s2 += v0 * v0 + v1 * v1;
            }
            s += __shfl_xor(s, 16); s += __shfl_xor(s, 32);
            s2 += __shfl_xor(s2, 16); s2 += __shfl_xor(s2, 32);
            float mu = s * (1.f / 64.f);
            float var = s2 * (1.f / 64.f) - mu * mu;
            float rr = rsqrtf(var + 1e-6f);
            short8 a0, a1;
#pragma unroll
            for (int j = 0; j < 8; j++) {
                a0[j] = f2bs((x[j] - mu) * rr * wc[j] + bc[j]);
                a1[j] = f2bs((x[8 + j] - mu) * rr * wc[8 + j] + bc[8 + j]);
            }
            afr0[i] = a0; afr1[i] = a1;
        }
    }

    const short* w1b = w1bf + b * 128 * 64;
    const float* w2b = w2n + b * 128 * 9;
    const float* b1b = b1 + b * 128;
    const float* b2b = b2v + b * 128;
    const int lx = t & 15, ly = t >> 4;

    for (int cc = 0; cc < 8; cc++) {
        // B fragment: cols n<8 -> out ch cc*8+n ; n>=8 -> cc*8+64+(n-8)
        int outch = cc * 8 + (n < 8 ? n : 56 + n);
        short8 bf0 = *(const short8*)(w1b + outch * 64 + q * 8);
        short8 bf1 = *(const short8*)(w1b + outch * 64 + 32 + q * 8);
        float bias = b1b[outch];
        short* sp = sP[cc & 1];
#pragma unroll
        for (int i = 0; i < 6; i++) {
            int mt = wave + i * 4;
            if (mt < 21) {
                f32x4 d = {0.f, 0.f, 0.f, 0.f};
                d = __builtin_amdgcn_mfma_f32_16x16x32_bf16(afr0[i], bf0, d, 0, 0, 0);
                d = __builtin_amdgcn_mfma_f32_16x16x32_bf16(afr1[i], bf1, d, 0, 0, 0);
#pragma unroll
                for (int r = 0; r < 4; r++) {
                    int row = mt * 16 + q * 4 + r;
                    if (row < 324) sp[row * 24 + n] = f2bs(d[r] + bias);
                }
            }
        }
        __syncthreads();
        // dw 3x3 + gate on the 16x16 tile for pairs cc*8 .. cc*8+7
        float accA[8], accB[8];
#pragma unroll
        for (int p = 0; p < 8; p++) {
            accA[p] = b2b[cc * 8 + p];
            accB[p] = b2b[64 + cc * 8 + p];
        }
#pragma unroll
        for (int ky = 0; ky < 3; ky++) {
#pragma unroll
            for (int kx = 0; kx < 3; kx++) {
                int yy = y0 + ly + ky - 1, xx = x0 + lx + kx - 1;
                bool valid = ((unsigned)yy < HN) && ((unsigned)xx < WN);
                int e = (ly + ky) * 18 + lx + kx;
                short8 pA = *(const short8*)&sp[e * 24];
                short8 pB = *(const short8*)&sp[e * 24 + 8];
#pragma unroll
                for (int p = 0; p < 8; p++) {
                    float va = valid ? bs2f(pA[p]) : 0.f;
                    float vb = valid ? bs2f(pB[p]) : 0.f;
                    accA[p] += va * w2b[(cc * 8 + p) * 9 + ky * 3 + kx];
                    accB[p] += vb * w2b[(64 + cc * 8 + p) * 9 + ky * 3 + kx];
                }
            }
        }
        size_t gbase = ((size_t)(b * 64 + cc * 8)) * HWN + (size_t)((y0 + ly) * WN + x0 + lx);
#pragma unroll
        for (int p = 0; p < 8; p++)
            g[gbase + ((size_t)p << 16)] = accA[p] * accB[p];
        // no trailing barrier: sP is double-buffered; the next cc writes the
        // other buffer, and the barrier inside cc+1 separates cc-reads from
        // cc+2-writes of the same buffer.
    }
}

// pooled[b][c] = sum over pixels of g  (one block per (b,c) — no atomics)
__global__ __launch_bounds__(1024) void k_pool(const float* __restrict__ g,
                                               float* __restrict__ pooled) {
    int bc = blockIdx.x;  // 0..511
    const float* src = g + (size_t)bc * HWN;
    float s = 0.f;
    for (int i = threadIdx.x * 4; i < HWN; i += 4096) {
        f32x4 v = *(const f32x4*)&src[i];
        s += v[0] + v[1] + v[2] + v[3];
    }
    __shared__ float red[16];
    int lane = threadIdx.x & 63, wave = threadIdx.x >> 6;
#pragma unroll
    for (int off = 32; off; off >>= 1) s += __shfl_down(s, off);
    if (lane == 0) red[wave] = s;
    __syncthreads();
    if (threadIdx.x < 16) {
        float v = red[threadIdx.x];
#pragma unroll
        for (int off = 8; off; off >>= 1) v += __shfl_down(v, off);
        if (threadIdx.x == 0) pooled[bc] = v;
    }
}

__global__ void k_sca(const float* __restrict__ pooled,
                      const float* __restrict__ scaw,
                      const float* __restrict__ scab,
                      float* __restrict__ sca) {
    int t = threadIdx.x;  // 512 = 8*64
    int b = t >> 6, o = t & 63;
    float acc = scab[o];
    for (int c = 0; c < 64; c++)
        acc += pooled[b * 64 + c] * (1.f / 65536.f) * scaw[o * 64 + c];
    sca[t] = acc;
}

// x=g*sca -> pw3(MFMA) -> y=inp+beta*x3 -> LN2 -> pw4(MFMA)+gate -> pw5(MFMA)
// -> out = y + gamma*x5.  g and out alias (d_out); block reads its own pixels
// in phase 1, writes them only in phase 6.
__global__ __launch_bounds__(256, 2) void k2(
    const float* __restrict__ inp, const float* g, const float* __restrict__ ws,
    const float* __restrict__ b3, const float* __restrict__ beta,
    const float* __restrict__ ln2w, const float* __restrict__ ln2b,
    const float* __restrict__ b4, const float* __restrict__ b5,
    const float* __restrict__ gamma, float* out) {
    const int b = blockIdx.x >> 9;
    const int px0 = (blockIdx.x & 511) << 7;  // 128 pixels per block
    const int t = threadIdx.x;
    const int wave = t >> 6, lane = t & 63;
    const int n = lane & 15, q = lane >> 4;

    __shared__ short sX[128 * 72];  // bf16 A-operand staging
    __shared__ short sY[64 * 136];  // bf16 y [ch][px]
    __shared__ short sH[128 * 72];  // bf16 h staging

    const float* scav = ws + SCA_OFF + b * 64;

    // phase 1: xg = g * sca -> sX
    {
        const float* gb = g + ((size_t)b << 22) + px0;
        for (int i = t; i < 128 * 64; i += 256) {
            int c = i >> 7, px = i & 127;
            sX[px * 72 + c] = f2bs(gb[((size_t)c << 16) + px] * scav[c]);
        }
    }
    __syncthreads();

    // phase 2: pw3 -> y -> sY
    {
        const short* w3b = (const short*)(ws + W3BF_OFF) + b * 64 * 64;
        const float* b3b = b3 + b * 64;
        for (int nc = 0; nc < 4; nc++) {
            int outch = nc * 16 + n;
            short8 bf0 = *(const short8*)(w3b + outch * 64 + q * 8);
            short8 bf1 = *(const short8*)(w3b + outch * 64 + 32 + q * 8);
            float b3v = b3b[outch], betav = beta[outch];
            const float* ib = inp + ((size_t)b << 22) + ((size_t)outch << 16) + px0;
            for (int mt = wave; mt < 8; mt += 4) {
                const short* arow = &sX[(mt * 16 + n) * 72];
                short8 a0 = *(const short8*)(arow + q * 8);
                short8 a1 = *(const short8*)(arow + 32 + q * 8);
                f32x4 d = {0.f, 0.f, 0.f, 0.f};
                d = __builtin_amdgcn_mfma_f32_16x16x32_bf16(a0, bf0, d, 0, 0, 0);
                d = __builtin_amdgcn_mfma_f32_16x16x32_bf16(a1, bf1, d, 0, 0, 0);
#pragma unroll
                for (int r = 0; r < 4; r++) {
                    int px = mt * 16 + q * 4 + r;
                    float y = ib[px] + betav * (d[r] + b3v);
                    sY[outch * 136 + px] = f2bs(y);
                }
            }
        }
    }
    __syncthreads();

    // phase 3: LN2 per pixel -> sX (normalized, bf16)
    if (t < 128) {
        float s = 0.f, s2 = 0.f;
        for (int c = 0; c < 64; c++) {
            float v = bs2f(sY[c * 136 + t]);
            s += v; s2 += v * v;
        }
        float mu = s * (1.f / 64.f);
        float var = s2 * (1.f / 64.f) - mu * mu;
        float rr = rsqrtf(var + 1e-6f);
        for (int c = 0; c < 64; c++) {
            float xn = (bs2f(sY[c * 136 + t]) - mu) * rr * ln2w[c] + ln2b[c];
            sX[t * 72 + c] = f2bs(xn);
        }
    }
    __syncthreads();

    // phase 4: pw4 + gate -> sH
    {
        const short* w4b = (const short*)(ws + W4BF_OFF) + b * 128 * 64;
        const float* b4b = b4 + b * 128;
        for (int cc = 0; cc < 8; cc++) {
            int outch = cc * 8 + (n < 8 ? n : 56 + n);
            short8 bf0 = *(const short8*)(w4b + outch * 64 + q * 8);
            short8 bf1 = *(const short8*)(w4b + outch * 64 + 32 + q * 8);
            float b4v = b4b[outch];
            for (int mt = wave; mt < 8; mt += 4) {
                const short* arow = &sX[(mt * 16 + n) * 72];
                short8 a0 = *(const short8*)(arow + q * 8);
                short8 a1 = *(const short8*)(arow + 32 + q * 8);
                f32x4 d = {0.f, 0.f, 0.f, 0.f};
                d = __builtin_amdgcn_mfma_f32_16x16x32_bf16(a0, bf0, d, 0, 0, 0);
                d = __builtin_amdgcn_mfma_f32_16x16x32_bf16(a1, bf1, d, 0, 0, 0);
#pragma unroll
                for (int r = 0; r < 4; r++) {
                    float val = d[r] + b4v;
                    float other = __shfl_xor(val, 8);
                    if (n < 8)
                        sH[(mt * 16 + q * 4 + r) * 72 + cc * 8 + n] = f2bs(val * other);
                }
            }
        }
    }
    __syncthreads();

    // phase 5: pw5 -> x5 -> sX
    {
        const short* w5b = (const short*)(ws + W5BF_OFF) + b * 64 * 64;
        const float* b5b = b5 + b * 64;
        for (int nc = 0; nc < 4; nc++) {
            int outch = nc * 16 + n;
            short8 bf0 = *(const short8*)(w5b + outch * 64 + q * 8);
            short8 bf1 = *(const short8*)(w5b + outch * 64 + 32 + q * 8);
            float b5v = b5b[outch];
            for (int mt = wave; mt < 8; mt += 4) {
                const short* arow = &sH[(mt * 16 + n) * 72];
                short8 a0 = *(const short8*)(arow + q * 8);
                short8 a1 = *(const short8*)(arow + 32 + q * 8);
                f32x4 d = {0.f, 0.f, 0.f, 0.f};
                d = __builtin_amdgcn_mfma_f32_16x16x32_bf16(a0, bf0, d, 0, 0, 0);
                d = __builtin_amdgcn_mfma_f32_16x16x32_bf16(a1, bf1, d, 0, 0, 0);
#pragma unroll
                for (int r = 0; r < 4; r++)
                    sX[(mt * 16 + q * 4 + r) * 72 + outch] = f2bs(d[r] + b5v);
            }
        }
    }
    __syncthreads();

    // phase 6: out = y + gamma * x5
    {
        int px = t & 127, half = t >> 7;
        float* ob = out + ((size_t)b << 22) + px0;
        for (int c = half * 32; c < half * 32 + 32; c++) {
            float o = bs2f(sY[c * 136 + px]) + gamma[c] * bs2f(sX[px * 72 + c]);
            ob[((size_t)c << 16) + px] = o;
        }
    }
}

extern "C" void kernel_launch(void* const* d_in, const int* in_sizes, int n_in,
                              void* d_out, int out_size, void* d_ws, size_t ws_size,
                              hipStream_t stream) {
    const float* inp  = (const float*)d_in[0];
    const float* w1   = (const float*)d_in[1];
    const float* b1   = (const float*)d_in[2];
    const float* w2   = (const float*)d_in[3];
    const float* b2v  = (const float*)d_in[4];
    const float* w3   = (const float*)d_in[5];
    const float* b3   = (const float*)d_in[6];
    const float* w4   = (const float*)d_in[7];
    const float* b4   = (const float*)d_in[8];
    const float* w5   = (const float*)d_in[9];
    const float* b5   = (const float*)d_in[10];
    const float* ln1w = (const float*)d_in[11];
    const float* ln1b = (const float*)d_in[12];
    const float* ln2w = (const float*)d_in[13];
    const float* ln2b = (const float*)d_in[14];
    const float* scaw = (const float*)d_in[15];
    const float* scab = (const float*)d_in[16];
    const float* beta = (const float*)d_in[17];
    const float* gamma= (const float*)d_in[18];

    float* ws = (float*)d_ws;
    float* pooled = ws + POOL_OFF;
    float* sca = ws + SCA_OFF;
    float* g = (float*)d_out;   // d_out doubles as scratch for the gated tensor
    float* out = (float*)d_out;

    k_prep<<<16, 256, 0, stream>>>(w1, w2, w3, w4, w5, ws);
    k1<<<2048, 256, 0, stream>>>(inp, ln1w, ln1b, b1, b2v, ws, g);
    k_pool<<<512, 1024, 0, stream>>>(g, pooled);
    k_sca<<<1, 512, 0, stream>>>(pooled, scaw, scab, sca);
    k2<<<4096, 256, 0, stream>>>(inp, g, ws, b3, beta, ln2w, ln2b, b4, b5,
                                 gamma, out);
}

// Round 3
// 593.245 us; speedup vs baseline: 1.4085x; 1.0666x over previous
//
#include <hip/hip_runtime.h>
#include <hip/hip_bf16.h>

typedef __attribute__((ext_vector_type(8))) short short8;
typedef __attribute__((ext_vector_type(4))) float f32x4;

#define HWN 65536
#define WN 256
#define HN 256

// ws float offsets
#define W2N_OFF 0            // 128*9*8 fp32 = 9216
#define W1BF_OFF 9216        // 8*128*64 bf16 = 32768 float slots
#define W3BF_OFF 41984       // 8*64*64 bf16 = 16384 float slots
#define W4BF_OFF 58368       // 8*128*64 bf16 = 32768 float slots
#define W5BF_OFF 91136       // 8*64*64 bf16 = 16384 float slots
#define POOL_OFF 107520      // 512 floats
#define SCA_OFF 108032       // 512 floats

static __device__ __forceinline__ short f2bs(float f) {
    union { __hip_bfloat16 h; short s; } u; u.h = __float2bfloat16(f); return u.s;
}
static __device__ __forceinline__ float bs2f(short s) {
    union { unsigned u; float f; } v; v.u = ((unsigned)(unsigned short)s) << 16; return v.f;
}

__device__ __forceinline__ void norm_row(const float* __restrict__ in,
                                         float* __restrict__ out, int n) {
    float s = 0.f;
    for (int i = 0; i < n; i++) { float v = in[i]; s += v * v; }
    float r = rsqrtf(s);
    for (int i = 0; i < n; i++) out[i] = in[i] * r;
}

__device__ __forceinline__ void norm_row_bf(const float* __restrict__ in,
                                            short* __restrict__ out, int n) {
    float s = 0.f;
    for (int i = 0; i < n; i++) { float v = in[i]; s += v * v; }
    float r = rsqrtf(s);
    for (int i = 0; i < n; i++) out[i] = f2bs(in[i] * r);
}

__global__ void k_prep(const float* __restrict__ w1, const float* __restrict__ w2,
                       const float* __restrict__ w3, const float* __restrict__ w4,
                       const float* __restrict__ w5, float* __restrict__ ws) {
    int r = blockIdx.x * 256 + threadIdx.x;
    short* w1bf = (short*)(ws + W1BF_OFF);
    short* w3bf = (short*)(ws + W3BF_OFF);
    short* w4bf = (short*)(ws + W4BF_OFF);
    short* w5bf = (short*)(ws + W5BF_OFF);
    if (r < 1024) {
        norm_row_bf(w1 + r * 64, w1bf + r * 64, 64);
    } else if (r < 2048) {
        int rr = r - 1024;
        norm_row(w2 + rr * 9, ws + W2N_OFF + rr * 9, 9);
    } else if (r < 2560) {
        int rr = r - 2048;
        norm_row_bf(w3 + rr * 64, w3bf + rr * 64, 64);
    } else if (r < 3584) {
        int rr = r - 2560;
        norm_row_bf(w4 + rr * 64, w4bf + rr * 64, 64);
    } else if (r < 4096) {
        int rr = r - 3584;
        norm_row_bf(w5 + rr * 64, w5bf + rr * 64, 64);
    } else if (r < 4608) {
        ws[POOL_OFF + (r - 4096)] = 0.f;   // zero pooled for k1's atomics
    }
}

// LN1 (regs, shfl) + pw1(MFMA) + dw3x3 + gate -> g, + fused channel pooling.
// sP split into two 16B-stride planes -> conflict-free ds_read_b128.
// OOB halo rows zeroed at write time (24-bit validity mask) -> dw loop has
// no boundary logic at all.
__global__ __launch_bounds__(256, 4) void k1(
    const float* __restrict__ inp, const float* __restrict__ ln1w,
    const float* __restrict__ ln1b, const float* __restrict__ b1,
    const float* __restrict__ b2v, const float* __restrict__ ws,
    float* __restrict__ g, float* __restrict__ pooled) {
    const short* w1bf = (const short*)(ws + W1BF_OFF);
    const float* w2n = ws + W2N_OFF;
    const int b = blockIdx.x >> 8;
    const int tile = blockIdx.x & 255;
    const int x0 = (tile & 15) << 4, y0 = (tile >> 4) << 4;
    const int t = threadIdx.x;
    const int wave = t >> 6, lane = t & 63;
    const int n = lane & 15, q = lane >> 4;

    __shared__ short sPA[2][324 * 8];  // bf16 [halo_pix][ch 0..7],  stride 16B
    __shared__ short sPB[2][324 * 8];  // bf16 [halo_pix][ch 8..15], stride 16B
    __shared__ float sRed[8 * 4 * 8];  // [cc][wave][p] pooling partials

    // per-lane LN coefs for channels q*8+j (j<8) and 32+q*8+j
    float wc[16], bc[16];
#pragma unroll
    for (int j = 0; j < 8; j++) {
        wc[j] = ln1w[q * 8 + j];
        bc[j] = ln1b[q * 8 + j];
        wc[8 + j] = ln1w[32 + q * 8 + j];
        bc[8 + j] = ln1b[32 + q * 8 + j];
    }

    // Phase A: LN1 into register A-fragments (wave owns mt = wave+4i).
    short8 afr0[6], afr1[6];
    const float* xb = inp + ((size_t)b << 22);
#pragma unroll
    for (int i = 0; i < 6; i++) {
        int mt = wave + i * 4;
        if (mt < 21) {
            int pix = mt * 16 + n;
            int hy = pix / 18, hx = pix - hy * 18;
            int yy = y0 - 1 + hy, xx = x0 - 1 + hx;
            bool inb = ((unsigned)yy < HN) && ((unsigned)xx < WN) && (pix < 324);
            const float* xin = xb + (yy * WN + xx);
            float x[16];
            float s = 0.f, s2 = 0.f;
#pragma unroll
            for (int j = 0; j < 8; j++) {
                float v0 = inb ? xin[(size_t)(q * 8 + j) << 16] : 0.f;
                float v1 = inb ? xin[(size_t)(32 + q * 8 + j) << 16] : 0.f;
                x[j] = v0; x[8 + j] = v1;
                s += v0 + v1; s2 += v0 * v0 + v1 * v1;
            }
            s += __shfl_xor(s, 16); s += __shfl_xor(s, 32);
            s2 += __shfl_xor(s2, 16); s2 += __shfl_xor(s2, 32);
            float mu = s * (1.f / 64.f);
            float var = s2 * (1.f / 64.f) - mu * mu;
            float rr = rsqrtf(var + 1e-6f);
            short8 a0, a1;
#pragma unroll
            for (int j = 0; j < 8; j++) {
                a0[j] = f2bs((x[j] - mu) * rr * wc[j] + bc[j]);
                a1[j] = f2bs((x[8 + j] - mu) * rr * wc[8 + j] + bc[8 + j]);
            }
            afr0[i] = a0; afr1[i] = a1;
        }
    }

    // validity mask for the 24 sP rows this thread writes (zero-pad OOB halo)
    unsigned vmask = 0;
#pragma unroll
    for (int i = 0; i < 6; i++) {
        int mt = wave + i * 4;
        if (mt < 21) {
#pragma unroll
            for (int r = 0; r < 4; r++) {
                int row = mt * 16 + q * 4 + r;
                int hy = row / 18, hx = row - hy * 18;
                int yy = y0 - 1 + hy, xx = x0 - 1 + hx;
                if (row < 324 && ((unsigned)yy < HN) && ((unsigned)xx < WN))
                    vmask |= 1u << (i * 4 + r);
            }
        }
    }

    const short* w1b = w1bf + b * 128 * 64;
    const float* w2b = w2n + b * 128 * 9;
    const float* b1b = b1 + b * 128;
    const float* b2b = b2v + b * 128;
    const int lx = t & 15, ly = t >> 4;

    for (int cc = 0; cc < 8; cc++) {
        // B fragment: cols n<8 -> out ch cc*8+n ; n>=8 -> cc*8+64+(n-8)
        int outch = cc * 8 + (n < 8 ? n : 56 + n);
        short8 bf0 = *(const short8*)(w1b + outch * 64 + q * 8);
        short8 bf1 = *(const short8*)(w1b + outch * 64 + 32 + q * 8);
        float bias = b1b[outch];
        short* spA = sPA[cc & 1];
        short* spB = sPB[cc & 1];
#pragma unroll
        for (int i = 0; i < 6; i++) {
            int mt = wave + i * 4;
            if (mt < 21) {
                f32x4 d = {0.f, 0.f, 0.f, 0.f};
                d = __builtin_amdgcn_mfma_f32_16x16x32_bf16(afr0[i], bf0, d, 0, 0, 0);
                d = __builtin_amdgcn_mfma_f32_16x16x32_bf16(afr1[i], bf1, d, 0, 0, 0);
#pragma unroll
                for (int r = 0; r < 4; r++) {
                    int row = mt * 16 + q * 4 + r;
                    short val = ((vmask >> (i * 4 + r)) & 1u) ? f2bs(d[r] + bias)
                                                              : (short)0;
                    if (row < 324) {
                        if (n < 8) spA[row * 8 + n] = val;
                        else       spB[row * 8 + (n - 8)] = val;
                    }
                }
            }
        }
        __syncthreads();
        // dw 3x3 + gate on the 16x16 tile, no boundary logic (sP zero-padded)
        float accA[8], accB[8];
#pragma unroll
        for (int p = 0; p < 8; p++) {
            accA[p] = b2b[cc * 8 + p];
            accB[p] = b2b[64 + cc * 8 + p];
        }
#pragma unroll
        for (int ky = 0; ky < 3; ky++) {
#pragma unroll
            for (int kx = 0; kx < 3; kx++) {
                int e = (ly + ky) * 18 + lx + kx;
                short8 pA = *(const short8*)&spA[e * 8];
                short8 pB = *(const short8*)&spB[e * 8];
#pragma unroll
                for (int p = 0; p < 8; p++) {
                    accA[p] += bs2f(pA[p]) * w2b[(cc * 8 + p) * 9 + ky * 3 + kx];
                    accB[p] += bs2f(pB[p]) * w2b[(64 + cc * 8 + p) * 9 + ky * 3 + kx];
                }
            }
        }
        float v[8];
        size_t gbase = ((size_t)(b * 64 + cc * 8)) * HWN + (size_t)((y0 + ly) * WN + x0 + lx);
#pragma unroll
        for (int p = 0; p < 8; p++) {
            v[p] = accA[p] * accB[p];
            g[gbase + ((size_t)p << 16)] = v[p];
        }
        // fused pooling: wave-reduce each channel, stash partial
#pragma unroll
        for (int p = 0; p < 8; p++) {
            float s = v[p];
            s += __shfl_xor(s, 1);  s += __shfl_xor(s, 2);
            s += __shfl_xor(s, 4);  s += __shfl_xor(s, 8);
            s += __shfl_xor(s, 16); s += __shfl_xor(s, 32);
            if (lane == 0) sRed[(cc * 4 + wave) * 8 + p] = s;
        }
        // no trailing barrier: sP double-buffered; cc+1's barrier separates
        // cc-reads from cc+2-writes of the same buffer.
    }
    __syncthreads();
    if (t < 64) {
        int cc = t >> 3, p = t & 7;
        float s = sRed[(cc * 4 + 0) * 8 + p] + sRed[(cc * 4 + 1) * 8 + p] +
                  sRed[(cc * 4 + 2) * 8 + p] + sRed[(cc * 4 + 3) * 8 + p];
        atomicAdd(&pooled[b * 64 + cc * 8 + p], s);
    }
}

__global__ void k_sca(const float* __restrict__ pooled,
                      const float* __restrict__ scaw,
                      const float* __restrict__ scab,
                      float* __restrict__ sca) {
    int t = threadIdx.x;  // 512 = 8*64
    int b = t >> 6, o = t & 63;
    float acc = scab[o];
    for (int c = 0; c < 64; c++)
        acc += pooled[b * 64 + c] * (1.f / 65536.f) * scaw[o * 64 + c];
    sca[t] = acc;
}

// x=g*sca -> pw3 -> y (REGISTERS + px-major LDS) -> LN2 (full-width) ->
// pw4+gate -> pw5 with fused epilogue out = y_reg + gamma*x5.
// Two LDS buffers (37 KB) -> 4 blocks/CU; 4 barriers.
__global__ __launch_bounds__(256, 4) void k2(
    const float* __restrict__ inp, const float* g, const float* __restrict__ ws,
    const float* __restrict__ b3, const float* __restrict__ beta,
    const float* __restrict__ ln2w, const float* __restrict__ ln2b,
    const float* __restrict__ b4, const float* __restrict__ b5,
    const float* __restrict__ gamma, float* out) {
    const int b = blockIdx.x >> 9;
    const int px0 = (blockIdx.x & 511) << 7;  // 128 pixels per block
    const int t = threadIdx.x;
    const int wave = t >> 6, lane = t & 63;
    const int n = lane & 15, q = lane >> 4;

    __shared__ short sX[128 * 72];  // A-operand staging (x, then LN2'd x)
    __shared__ short sB[128 * 72];  // y px-major (ph2-3), then h (ph4-5)

    const float* scav = ws + SCA_OFF + b * 64;

    // phase 1: xg = g * sca -> sX [px][c]
    {
        const float* gb = g + ((size_t)b << 22) + px0;
        for (int i = t; i < 128 * 64; i += 256) {
            int c = i >> 7, px = i & 127;
            sX[px * 72 + c] = f2bs(gb[((size_t)c << 16) + px] * scav[c]);
        }
    }
    __syncthreads();

    // phase 2: pw3 -> y; keep y in registers AND write px-major to sB
    float yreg[4][2][4];
    {
        const short* w3b = (const short*)(ws + W3BF_OFF) + b * 64 * 64;
        const float* b3b = b3 + b * 64;
#pragma unroll
        for (int nc = 0; nc < 4; nc++) {
            int outch = nc * 16 + n;
            short8 bf0 = *(const short8*)(w3b + outch * 64 + q * 8);
            short8 bf1 = *(const short8*)(w3b + outch * 64 + 32 + q * 8);
            float b3v = b3b[outch], betav = beta[outch];
            const float* ib = inp + ((size_t)b << 22) + ((size_t)outch << 16) + px0;
#pragma unroll
            for (int mi = 0; mi < 2; mi++) {
                int mt = wave + mi * 4;
                const short* arow = &sX[(mt * 16 + n) * 72];
                short8 a0 = *(const short8*)(arow + q * 8);
                short8 a1 = *(const short8*)(arow + 32 + q * 8);
                f32x4 d = {0.f, 0.f, 0.f, 0.f};
                d = __builtin_amdgcn_mfma_f32_16x16x32_bf16(a0, bf0, d, 0, 0, 0);
                d = __builtin_amdgcn_mfma_f32_16x16x32_bf16(a1, bf1, d, 0, 0, 0);
                f32x4 resid = *(const f32x4*)(ib + mt * 16 + q * 4);
#pragma unroll
                for (int r = 0; r < 4; r++) {
                    float y = resid[r] + betav * (d[r] + b3v);
                    yreg[nc][mi][r] = y;
                    sB[(mt * 16 + q * 4 + r) * 72 + outch] = f2bs(y);
                }
            }
        }
    }
    __syncthreads();

    // phase 3: LN2, 2 threads per pixel, vector LDS reads, shfl combine
    {
        int px = t >> 1, half = t & 1;
        const short* yrow = &sB[px * 72 + half * 32];
        short8 yv[4];
        float s = 0.f, s2 = 0.f;
#pragma unroll
        for (int v8 = 0; v8 < 4; v8++) {
            yv[v8] = *(const short8*)(yrow + v8 * 8);
#pragma unroll
            for (int j = 0; j < 8; j++) {
                float f = bs2f(yv[v8][j]);
                s += f; s2 += f * f;
            }
        }
        s += __shfl_xor(s, 1); s2 += __shfl_xor(s2, 1);
        float mu = s * (1.f / 64.f);
        float var = s2 * (1.f / 64.f) - mu * mu;
        float rr = rsqrtf(var + 1e-6f);
        short* xrow = &sX[px * 72 + half * 32];
#pragma unroll
        for (int v8 = 0; v8 < 4; v8++) {
            short8 o;
#pragma unroll
            for (int j = 0; j < 8; j++) {
                int c = half * 32 + v8 * 8 + j;
                o[j] = f2bs((bs2f(yv[v8][j]) - mu) * rr * ln2w[c] + ln2b[c]);
            }
            *(short8*)(xrow + v8 * 8) = o;
        }
    }
    __syncthreads();

    // phase 4: pw4 + gate -> sB (y no longer needed in LDS)
    {
        const short* w4b = (const short*)(ws + W4BF_OFF) + b * 128 * 64;
        const float* b4b = b4 + b * 128;
        for (int cc = 0; cc < 8; cc++) {
            int outch = cc * 8 + (n < 8 ? n : 56 + n);
            short8 bf0 = *(const short8*)(w4b + outch * 64 + q * 8);
            short8 bf1 = *(const short8*)(w4b + outch * 64 + 32 + q * 8);
            float b4v = b4b[outch];
#pragma unroll
            for (int mi = 0; mi < 2; mi++) {
                int mt = wave + mi * 4;
                const short* arow = &sX[(mt * 16 + n) * 72];
                short8 a0 = *(const short8*)(arow + q * 8);
                short8 a1 = *(const short8*)(arow + 32 + q * 8);
                f32x4 d = {0.f, 0.f, 0.f, 0.f};
                d = __builtin_amdgcn_mfma_f32_16x16x32_bf16(a0, bf0, d, 0, 0, 0);
                d = __builtin_amdgcn_mfma_f32_16x16x32_bf16(a1, bf1, d, 0, 0, 0);
#pragma unroll
                for (int r = 0; r < 4; r++) {
                    float val = d[r] + b4v;
                    float other = __shfl_xor(val, 8);
                    if (n < 8)
                        sB[(mt * 16 + q * 4 + r) * 72 + cc * 8 + n] = f2bs(val * other);
                }
            }
        }
    }
    __syncthreads();

    // phase 5: pw5 + fused epilogue: out = y_reg + gamma * (pw5 + b5)
    {
        const short* w5b = (const short*)(ws + W5BF_OFF) + b * 64 * 64;
        const float* b5b = b5 + b * 64;
        float* ob = out + ((size_t)b << 22) + px0;
#pragma unroll
        for (int nc = 0; nc < 4; nc++) {
            int outch = nc * 16 + n;
            short8 bf0 = *(const short8*)(w5b + outch * 64 + q * 8);
            short8 bf1 = *(const short8*)(w5b + outch * 64 + 32 + q * 8);
            float b5v = b5b[outch], gam = gamma[outch];
#pragma unroll
            for (int mi = 0; mi < 2; mi++) {
                int mt = wave + mi * 4;
                const short* arow = &sB[(mt * 16 + n) * 72];
                short8 a0 = *(const short8*)(arow + q * 8);
                short8 a1 = *(const short8*)(arow + 32 + q * 8);
                f32x4 d = {0.f, 0.f, 0.f, 0.f};
                d = __builtin_amdgcn_mfma_f32_16x16x32_bf16(a0, bf0, d, 0, 0, 0);
                d = __builtin_amdgcn_mfma_f32_16x16x32_bf16(a1, bf1, d, 0, 0, 0);
                f32x4 o;
#pragma unroll
                for (int r = 0; r < 4; r++)
                    o[r] = yreg[nc][mi][r] + gam * (d[r] + b5v);
                *(f32x4*)(ob + ((size_t)outch << 16) + mt * 16 + q * 4) = o;
            }
        }
    }
}

extern "C" void kernel_launch(void* const* d_in, const int* in_sizes, int n_in,
                              void* d_out, int out_size, void* d_ws, size_t ws_size,
                              hipStream_t stream) {
    const float* inp  = (const float*)d_in[0];
    const float* w1   = (const float*)d_in[1];
    const float* b1   = (const float*)d_in[2];
    const float* w2   = (const float*)d_in[3];
    const float* b2v  = (const float*)d_in[4];
    const float* w3   = (const float*)d_in[5];
    const float* b3   = (const float*)d_in[6];
    const float* w4   = (const float*)d_in[7];
    const float* b4   = (const float*)d_in[8];
    const float* w5   = (const float*)d_in[9];
    const float* b5   = (const float*)d_in[10];
    const float* ln1w = (const float*)d_in[11];
    const float* ln1b = (const float*)d_in[12];
    const float* ln2w = (const float*)d_in[13];
    const float* ln2b = (const float*)d_in[14];
    const float* scaw = (const float*)d_in[15];
    const float* scab = (const float*)d_in[16];
    const float* beta = (const float*)d_in[17];
    const float* gamma= (const float*)d_in[18];

    float* ws = (float*)d_ws;
    float* pooled = ws + POOL_OFF;
    float* sca = ws + SCA_OFF;
    float* g = (float*)d_out;   // d_out doubles as scratch for the gated tensor
    float* out = (float*)d_out;

    k_prep<<<17, 256, 0, stream>>>(w1, w2, w3, w4, w5, ws);
    k1<<<2048, 256, 0, stream>>>(inp, ln1w, ln1b, b1, b2v, ws, g, pooled);
    k_sca<<<1, 512, 0, stream>>>(pooled, scaw, scab, sca);
    k2<<<4096, 256, 0, stream>>>(inp, g, ws, b3, beta, ln2w, ln2b, b4, b5,
                                 gamma, out);
}

// Round 5
// 533.044 us; speedup vs baseline: 1.5676x; 1.1129x over previous
//
#include <hip/hip_runtime.h>
#include <hip/hip_bf16.h>

typedef __attribute__((ext_vector_type(8))) short short8;
typedef __attribute__((ext_vector_type(4))) float f32x4;

#define HWN 65536
#define WN 256
#define HN 256

// k1 tile geometry: 32 wide x 8 tall (g rows = full 128B lines)
#define TW 32
#define TH 8
#define HALO_W 34
#define HALO_N 340   // 34 * 10
#define MT_N 22      // ceil(340/16)

// ws float offsets
#define W2N_OFF 0            // 128*9*8 fp32 = 9216
#define W1BF_OFF 9216        // 8*128*64 bf16 = 32768 float slots
#define W3BF_OFF 41984       // 8*64*64 bf16 = 16384 float slots
#define W4BF_OFF 58368       // 8*128*64 bf16 = 32768 float slots
#define W5BF_OFF 91136       // 8*64*64 bf16 = 16384 float slots
#define POOL_OFF 107520      // 512 floats
#define SCA_OFF 108032       // 512 floats

static __device__ __forceinline__ short f2bs(float f) {
    union { __hip_bfloat16 h; short s; } u; u.h = __float2bfloat16(f); return u.s;
}
static __device__ __forceinline__ float bs2f(short s) {
    union { unsigned u; float f; } v; v.u = ((unsigned)(unsigned short)s) << 16; return v.f;
}

__device__ __forceinline__ void norm_row(const float* __restrict__ in,
                                         float* __restrict__ out, int n) {
    float s = 0.f;
    for (int i = 0; i < n; i++) { float v = in[i]; s += v * v; }
    float r = rsqrtf(s);
    for (int i = 0; i < n; i++) out[i] = in[i] * r;
}

__device__ __forceinline__ void norm_row_bf(const float* __restrict__ in,
                                            short* __restrict__ out, int n) {
    float s = 0.f;
    for (int i = 0; i < n; i++) { float v = in[i]; s += v * v; }
    float r = rsqrtf(s);
    for (int i = 0; i < n; i++) out[i] = f2bs(in[i] * r);
}

__global__ void k_prep(const float* __restrict__ w1, const float* __restrict__ w2,
                       const float* __restrict__ w3, const float* __restrict__ w4,
                       const float* __restrict__ w5, float* __restrict__ ws) {
    int r = blockIdx.x * 256 + threadIdx.x;
    short* w1bf = (short*)(ws + W1BF_OFF);
    short* w3bf = (short*)(ws + W3BF_OFF);
    short* w4bf = (short*)(ws + W4BF_OFF);
    short* w5bf = (short*)(ws + W5BF_OFF);
    if (r < 1024) {
        norm_row_bf(w1 + r * 64, w1bf + r * 64, 64);
    } else if (r < 2048) {
        int rr = r - 1024;
        norm_row(w2 + rr * 9, ws + W2N_OFF + rr * 9, 9);
    } else if (r < 2560) {
        int rr = r - 2048;
        norm_row_bf(w3 + rr * 64, w3bf + rr * 64, 64);
    } else if (r < 3584) {
        int rr = r - 2560;
        norm_row_bf(w4 + rr * 64, w4bf + rr * 64, 64);
    } else if (r < 4096) {
        int rr = r - 3584;
        norm_row_bf(w5 + rr * 64, w5bf + rr * 64, 64);
    } else if (r < 4608) {
        ws[POOL_OFF + (r - 4096)] = 0.f;   // zero pooled for k1's atomics
    }
}

// LN1 (regs, shfl) + pw1(MFMA) + dw3x3 + gate -> g, + fused channel pooling.
// 32x8 output tile: every g row is one aligned 128B line (no partial-line
// writeback).  launch_bounds(256,3): register budget ~170 -> no scratch
// spills (round-3 regression: bounds(256,4) forced VGPR=64 -> ~150MB spill
// traffic).
__global__ __launch_bounds__(256, 3) void k1(
    const float* __restrict__ inp, const float* __restrict__ ln1w,
    const float* __restrict__ ln1b, const float* __restrict__ b1,
    const float* __restrict__ b2v, const float* __restrict__ ws,
    float* __restrict__ g, float* __restrict__ pooled) {
    const short* w1bf = (const short*)(ws + W1BF_OFF);
    const float* w2n = ws + W2N_OFF;
    const int b = blockIdx.x >> 8;
    const int tile = blockIdx.x & 255;
    const int x0 = (tile & 7) << 5, y0 = (tile >> 3) << 3;
    const int t = threadIdx.x;
    const int wave = t >> 6, lane = t & 63;
    const int n = lane & 15, q = lane >> 4;

    __shared__ short sPA[2][HALO_N * 8];  // bf16 [halo_pix][ch 0..7],  16B rows
    __shared__ short sPB[2][HALO_N * 8];  // bf16 [halo_pix][ch 8..15], 16B rows
    __shared__ float sRed[8 * 4 * 8];     // [cc][wave][p] pooling partials

    // per-lane LN coefs for channels q*8+j (j<8) and 32+q*8+j
    float wc[16], bc[16];
#pragma unroll
    for (int j = 0; j < 8; j++) {
        wc[j] = ln1w[q * 8 + j];
        bc[j] = ln1b[q * 8 + j];
        wc[8 + j] = ln1w[32 + q * 8 + j];
        bc[8 + j] = ln1b[32 + q * 8 + j];
    }

    // Phase A: LN1 into register A-fragments (wave owns mt = wave+4i).
    short8 afr0[6], afr1[6];
    const float* xb = inp + ((size_t)b << 22);
#pragma unroll
    for (int i = 0; i < 6; i++) {
        int mt = wave + i * 4;
        if (mt < MT_N) {
            int pix = mt * 16 + n;
            int hy = pix / HALO_W, hx = pix - hy * HALO_W;
            int yy = y0 - 1 + hy, xx = x0 - 1 + hx;
            bool inb = ((unsigned)yy < HN) && ((unsigned)xx < WN) && (pix < HALO_N);
            const float* xin = xb + (yy * WN + xx);
            float x[16];
            float s = 0.f, s2 = 0.f;
#pragma unroll
            for (int j = 0; j < 8; j++) {
                float v0 = inb ? xin[(size_t)(q * 8 + j) << 16] : 0.f;
                float v1 = inb ? xin[(size_t)(32 + q * 8 + j) << 16] : 0.f;
                x[j] = v0; x[8 + j] = v1;
                s += v0 + v1; s2 += v0 * v0 + v1 * v1;
            }
            s += __shfl_xor(s, 16); s += __shfl_xor(s, 32);
            s2 += __shfl_xor(s2, 16); s2 += __shfl_xor(s2, 32);
            float mu = s * (1.f / 64.f);
            float var = s2 * (1.f / 64.f) - mu * mu;
            float rr = rsqrtf(var + 1e-6f);
            short8 a0, a1;
#pragma unroll
            for (int j = 0; j < 8; j++) {
                a0[j] = f2bs((x[j] - mu) * rr * wc[j] + bc[j]);
                a1[j] = f2bs((x[8 + j] - mu) * rr * wc[8 + j] + bc[8 + j]);
            }
            afr0[i] = a0; afr1[i] = a1;
        }
    }

    // validity mask for the 24 sP rows this thread writes (zero-pad OOB halo)
    unsigned vmask = 0;
#pragma unroll
    for (int i = 0; i < 6; i++) {
        int mt = wave + i * 4;
        if (mt < MT_N) {
#pragma unroll
            for (int r = 0; r < 4; r++) {
                int row = mt * 16 + q * 4 + r;
                int hy = row / HALO_W, hx = row - hy * HALO_W;
                int yy = y0 - 1 + hy, xx = x0 - 1 + hx;
                if (row < HALO_N && ((unsigned)yy < HN) && ((unsigned)xx < WN))
                    vmask |= 1u << (i * 4 + r);
            }
        }
    }

    const short* w1b = w1bf + b * 128 * 64;
    const float* w2b = w2n + b * 128 * 9;
    const float* b1b = b1 + b * 128;
    const float* b2b = b2v + b * 128;
    const int lx = t & 31, ly = t >> 5;  // 32x8 output tile

    for (int cc = 0; cc < 8; cc++) {
        // B fragment: cols n<8 -> out ch cc*8+n ; n>=8 -> cc*8+64+(n-8)
        int outch = cc * 8 + (n < 8 ? n : 56 + n);
        short8 bf0 = *(const short8*)(w1b + outch * 64 + q * 8);
        short8 bf1 = *(const short8*)(w1b + outch * 64 + 32 + q * 8);
        float bias = b1b[outch];
        short* spA = sPA[cc & 1];
        short* spB = sPB[cc & 1];
#pragma unroll
        for (int i = 0; i < 6; i++) {
            int mt = wave + i * 4;
            if (mt < MT_N) {
                f32x4 d = {0.f, 0.f, 0.f, 0.f};
                d = __builtin_amdgcn_mfma_f32_16x16x32_bf16(afr0[i], bf0, d, 0, 0, 0);
                d = __builtin_amdgcn_mfma_f32_16x16x32_bf16(afr1[i], bf1, d, 0, 0, 0);
#pragma unroll
                for (int r = 0; r < 4; r++) {
                    int row = mt * 16 + q * 4 + r;
                    short val = ((vmask >> (i * 4 + r)) & 1u) ? f2bs(d[r] + bias)
                                                              : (short)0;
                    if (row < HALO_N) {
                        if (n < 8) spA[row * 8 + n] = val;
                        else       spB[row * 8 + (n - 8)] = val;
                    }
                }
            }
        }
        __syncthreads();
        // dw 3x3 + gate on the 32x8 tile, no boundary logic (sP zero-padded)
        float accA[8], accB[8];
#pragma unroll
        for (int p = 0; p < 8; p++) {
            accA[p] = b2b[cc * 8 + p];
            accB[p] = b2b[64 + cc * 8 + p];
        }
#pragma unroll
        for (int ky = 0; ky < 3; ky++) {
#pragma unroll
            for (int kx = 0; kx < 3; kx++) {
                int e = (ly + ky) * HALO_W + lx + kx;
                short8 pA = *(const short8*)&spA[e * 8];
                short8 pB = *(const short8*)&spB[e * 8];
#pragma unroll
                for (int p = 0; p < 8; p++) {
                    accA[p] += bs2f(pA[p]) * w2b[(cc * 8 + p) * 9 + ky * 3 + kx];
                    accB[p] += bs2f(pB[p]) * w2b[(64 + cc * 8 + p) * 9 + ky * 3 + kx];
                }
            }
        }
        float v[8];
        size_t gbase = ((size_t)(b * 64 + cc * 8)) * HWN + (size_t)((y0 + ly) * WN + x0 + lx);
#pragma unroll
        for (int p = 0; p < 8; p++) {
            v[p] = accA[p] * accB[p];
            g[gbase + ((size_t)p << 16)] = v[p];
        }
        // fused pooling: wave-reduce each channel, stash partial
#pragma unroll
        for (int p = 0; p < 8; p++) {
            float s = v[p];
            s += __shfl_xor(s, 1);  s += __shfl_xor(s, 2);
            s += __shfl_xor(s, 4);  s += __shfl_xor(s, 8);
            s += __shfl_xor(s, 16); s += __shfl_xor(s, 32);
            if (lane == 0) sRed[(cc * 4 + wave) * 8 + p] = s;
        }
        // no trailing barrier: sP double-buffered; cc+1's barrier separates
        // cc-reads from cc+2-writes of the same buffer.
    }
    __syncthreads();
    if (t < 64) {
        int cc = t >> 3, p = t & 7;
        float s = sRed[(cc * 4 + 0) * 8 + p] + sRed[(cc * 4 + 1) * 8 + p] +
                  sRed[(cc * 4 + 2) * 8 + p] + sRed[(cc * 4 + 3) * 8 + p];
        atomicAdd(&pooled[b * 64 + cc * 8 + p], s);
    }
}

__global__ void k_sca(const float* __restrict__ pooled,
                      const float* __restrict__ scaw,
                      const float* __restrict__ scab,
                      float* __restrict__ sca) {
    int t = threadIdx.x;  // 512 = 8*64
    int b = t >> 6, o = t & 63;
    float acc = scab[o];
    for (int c = 0; c < 64; c++)
        acc += pooled[b * 64 + c] * (1.f / 65536.f) * scaw[o * 64 + c];
    sca[t] = acc;
}

// x=g*sca -> pw3 -> y (REGISTERS + px-major LDS) -> LN2 (full-width) ->
// pw4+gate -> pw5 with fused epilogue out = y_reg + gamma*x5.
// Two LDS buffers (37 KB) -> 4 blocks/CU; 4 barriers.
__global__ __launch_bounds__(256, 4) void k2(
    const float* __restrict__ inp, const float* g, const float* __restrict__ ws,
    const float* __restrict__ b3, const float* __restrict__ beta,
    const float* __restrict__ ln2w, const float* __restrict__ ln2b,
    const float* __restrict__ b4, const float* __restrict__ b5,
    const float* __restrict__ gamma, float* out) {
    const int b = blockIdx.x >> 9;
    const int px0 = (blockIdx.x & 511) << 7;  // 128 pixels per block
    const int t = threadIdx.x;
    const int wave = t >> 6, lane = t & 63;
    const int n = lane & 15, q = lane >> 4;

    __shared__ short sX[128 * 72];  // A-operand staging (x, then LN2'd x)
    __shared__ short sB[128 * 72];  // y px-major (ph2-3), then h (ph4-5)

    const float* scav = ws + SCA_OFF + b * 64;

    // phase 1: xg = g * sca -> sX [px][c]
    {
        const float* gb = g + ((size_t)b << 22) + px0;
        for (int i = t; i < 128 * 64; i += 256) {
            int c = i >> 7, px = i & 127;
            sX[px * 72 + c] = f2bs(gb[((size_t)c << 16) + px] * scav[c]);
        }
    }
    __syncthreads();

    // phase 2: pw3 -> y; keep y in registers AND write px-major to sB
    float yreg[4][2][4];
    {
        const short* w3b = (const short*)(ws + W3BF_OFF) + b * 64 * 64;
        const float* b3b = b3 + b * 64;
#pragma unroll
        for (int nc = 0; nc < 4; nc++) {
            int outch = nc * 16 + n;
            short8 bf0 = *(const short8*)(w3b + outch * 64 + q * 8);
            short8 bf1 = *(const short8*)(w3b + outch * 64 + 32 + q * 8);
            float b3v = b3b[outch], betav = beta[outch];
            const float* ib = inp + ((size_t)b << 22) + ((size_t)outch << 16) + px0;
#pragma unroll
            for (int mi = 0; mi < 2; mi++) {
                int mt = wave + mi * 4;
                const short* arow = &sX[(mt * 16 + n) * 72];
                short8 a0 = *(const short8*)(arow + q * 8);
                short8 a1 = *(const short8*)(arow + 32 + q * 8);
                f32x4 d = {0.f, 0.f, 0.f, 0.f};
                d = __builtin_amdgcn_mfma_f32_16x16x32_bf16(a0, bf0, d, 0, 0, 0);
                d = __builtin_amdgcn_mfma_f32_16x16x32_bf16(a1, bf1, d, 0, 0, 0);
                f32x4 resid = *(const f32x4*)(ib + mt * 16 + q * 4);
#pragma unroll
                for (int r = 0; r < 4; r++) {
                    float y = resid[r] + betav * (d[r] + b3v);
                    yreg[nc][mi][r] = y;
                    sB[(mt * 16 + q * 4 + r) * 72 + outch] = f2bs(y);
                }
            }
        }
    }
    __syncthreads();

    // phase 3: LN2, 2 threads per pixel, vector LDS reads, shfl combine
    {
        int px = t >> 1, half = t & 1;
        const short* yrow = &sB[px * 72 + half * 32];
        short8 yv[4];
        float s = 0.f, s2 = 0.f;
#pragma unroll
        for (int v8 = 0; v8 < 4; v8++) {
            yv[v8] = *(const short8*)(yrow + v8 * 8);
#pragma unroll
            for (int j = 0; j < 8; j++) {
                float f = bs2f(yv[v8][j]);
                s += f; s2 += f * f;
            }
        }
        s += __shfl_xor(s, 1); s2 += __shfl_xor(s2, 1);
        float mu = s * (1.f / 64.f);
        float var = s2 * (1.f / 64.f) - mu * mu;
        float rr = rsqrtf(var + 1e-6f);
        short* xrow = &sX[px * 72 + half * 32];
#pragma unroll
        for (int v8 = 0; v8 < 4; v8++) {
            short8 o;
#pragma unroll
            for (int j = 0; j < 8; j++) {
                int c = half * 32 + v8 * 8 + j;
                o[j] = f2bs((bs2f(yv[v8][j]) - mu) * rr * ln2w[c] + ln2b[c]);
            }
            *(short8*)(xrow + v8 * 8) = o;
        }
    }
    __syncthreads();

    // phase 4: pw4 + gate -> sB (y no longer needed in LDS)
    {
        const short* w4b = (const short*)(ws + W4BF_OFF) + b * 128 * 64;
        const float* b4b = b4 + b * 128;
        for (int cc = 0; cc < 8; cc++) {
            int outch = cc * 8 + (n < 8 ? n : 56 + n);
            short8 bf0 = *(const short8*)(w4b + outch * 64 + q * 8);
            short8 bf1 = *(const short8*)(w4b + outch * 64 + 32 + q * 8);
            float b4v = b4b[outch];
#pragma unroll
            for (int mi = 0; mi < 2; mi++) {
                int mt = wave + mi * 4;
                const short* arow = &sX[(mt * 16 + n) * 72];
                short8 a0 = *(const short8*)(arow + q * 8);
                short8 a1 = *(const short8*)(arow + 32 + q * 8);
                f32x4 d = {0.f, 0.f, 0.f, 0.f};
                d = __builtin_amdgcn_mfma_f32_16x16x32_bf16(a0, bf0, d, 0, 0, 0);
                d = __builtin_amdgcn_mfma_f32_16x16x32_bf16(a1, bf1, d, 0, 0, 0);
#pragma unroll
                for (int r = 0; r < 4; r++) {
                    float val = d[r] + b4v;
                    float other = __shfl_xor(val, 8);
                    if (n < 8)
                        sB[(mt * 16 + q * 4 + r) * 72 + cc * 8 + n] = f2bs(val * other);
                }
            }
        }
    }
    __syncthreads();

    // phase 5: pw5 + fused epilogue: out = y_reg + gamma * (pw5 + b5)
    {
        const short* w5b = (const short*)(ws + W5BF_OFF) + b * 64 * 64;
        const float* b5b = b5 + b * 64;
        float* ob = out + ((size_t)b << 22) + px0;
#pragma unroll
        for (int nc = 0; nc < 4; nc++) {
            int outch = nc * 16 + n;
            short8 bf0 = *(const short8*)(w5b + outch * 64 + q * 8);
            short8 bf1 = *(const short8*)(w5b + outch * 64 + 32 + q * 8);
            float b5v = b5b[outch], gam = gamma[outch];
#pragma unroll
            for (int mi = 0; mi < 2; mi++) {
                int mt = wave + mi * 4;
                const short* arow = &sB[(mt * 16 + n) * 72];
                short8 a0 = *(const short8*)(arow + q * 8);
                short8 a1 = *(const short8*)(arow + 32 + q * 8);
                f32x4 d = {0.f, 0.f, 0.f, 0.f};
                d = __builtin_amdgcn_mfma_f32_16x16x32_bf16(a0, bf0, d, 0, 0, 0);
                d = __builtin_amdgcn_mfma_f32_16x16x32_bf16(a1, bf1, d, 0, 0, 0);
                f32x4 o;
#pragma unroll
                for (int r = 0; r < 4; r++)
                    o[r] = yreg[nc][mi][r] + gam * (d[r] + b5v);
                *(f32x4*)(ob + ((size_t)outch << 16) + mt * 16 + q * 4) = o;
            }
        }
    }
}

extern "C" void kernel_launch(void* const* d_in, const int* in_sizes, int n_in,
                              void* d_out, int out_size, void* d_ws, size_t ws_size,
                              hipStream_t stream) {
    const float* inp  = (const float*)d_in[0];
    const float* w1   = (const float*)d_in[1];
    const float* b1   = (const float*)d_in[2];
    const float* w2   = (const float*)d_in[3];
    const float* b2v  = (const float*)d_in[4];
    const float* w3   = (const float*)d_in[5];
    const float* b3   = (const float*)d_in[6];
    const float* w4   = (const float*)d_in[7];
    const float* b4   = (const float*)d_in[8];
    const float* w5   = (const float*)d_in[9];
    const float* b5   = (const float*)d_in[10];
    const float* ln1w = (const float*)d_in[11];
    const float* ln1b = (const float*)d_in[12];
    const float* ln2w = (const float*)d_in[13];
    const float* ln2b = (const float*)d_in[14];
    const float* scaw = (const float*)d_in[15];
    const float* scab = (const float*)d_in[16];
    const float* beta = (const float*)d_in[17];
    const float* gamma= (const float*)d_in[18];

    float* ws = (float*)d_ws;
    float* pooled = ws + POOL_OFF;
    float* sca = ws + SCA_OFF;
    float* g = (float*)d_out;   // d_out doubles as scratch for the gated tensor
    float* out = (float*)d_out;

    k_prep<<<17, 256, 0, stream>>>(w1, w2, w3, w4, w5, ws);
    k1<<<2048, 256, 0, stream>>>(inp, ln1w, ln1b, b1, b2v, ws, g, pooled);
    k_sca<<<1, 512, 0, stream>>>(pooled, scaw, scab, sca);
    k2<<<4096, 256, 0, stream>>>(inp, g, ws, b3, beta, ln2w, ln2b, b4, b5,
                                 gamma, out);
}